// Round 11
// baseline (128.501 us; speedup 1.0000x reference)
//
#include <hip/hip_runtime.h>
#include <cstddef>

// ----------------------------------------------------------------------------
// AttentionFusion round 10: 6 launches. scores_ctx rebuilt: 8-wave blocks
// (wave (n,r) = head n, t-row r), batched uint4 LDS reads (round-2 geometry),
// py panel shared by 2 waves. Rest identical to round 9 (127.8us).
// ----------------------------------------------------------------------------

#define D_  768
#define HD_ 768
#define NH_ 4
#define B_  4
#define T1_ 128
#define T2_ 128
#define M_  (B_*T1_)
#define LN_EPS_ 1e-5f

typedef unsigned short u16;
typedef unsigned int u32;
typedef _Float16 f16;
typedef _Float16 f16x2 __attribute__((ext_vector_type(2)));
typedef __bf16 bf16x8 __attribute__((ext_vector_type(8)));
typedef float f32x4 __attribute__((ext_vector_type(4)));

__device__ __forceinline__ u16 f2bf(float f) {
    union { float f; unsigned int u; } v; v.f = f;
    unsigned int u = v.u + (0x7FFFu + ((v.u >> 16) & 1u));
    return (u16)(u >> 16);
}
__device__ __forceinline__ u32 pack_bf2(float lo, float hi) {
    return (u32)f2bf(lo) | ((u32)f2bf(hi) << 16);
}
__device__ __forceinline__ u16 f16bits(f16 h) {
    return __builtin_bit_cast(unsigned short, h);
}
__device__ __forceinline__ f16x2 bcast2(u32 u) {
    return __builtin_bit_cast(f16x2, u);
}
__device__ __forceinline__ u32 splat2(u16 h) { return (u32)h * 0x10001u; }

// ---------------- bf16 MFMA GEMM: C[M,N] = A[M,K] @ Bt[N,K]^T + bias --------
// AF32: A is f32 (converted to bf16 during staging). Else A is bf16.
// MODE: 0 = f32 rows, 1 = bf16 rows, 2 = f16 rows, 3 = f16 transposed (py_t)
template<bool RELU, int MODE, bool AF32>
__device__ __forceinline__ void gemm_mfma_body(
    const void* __restrict__ Av, int lda,
    const u16* __restrict__ Bt, int ldb,
    const float* __restrict__ bias,
    void* __restrict__ C, int ldc, int K, int m0, int n0)
{
    __shared__ __align__(16) u16 As[64][40];
    __shared__ __align__(16) u16 Bs[64][40];
    __shared__ u16 Ts[MODE == 3 ? 64 : 1][MODE == 3 ? 68 : 1];

    const int tid = threadIdx.x;
    const int row = tid >> 2;
    const int kq  = (tid & 3) << 3;
    const int lane = tid & 63;
    const int w  = tid >> 6;
    const int wr = (w >> 1) << 5;
    const int wc = (w & 1) << 5;
    const int l16 = lane & 15;
    const int lk8 = (lane >> 4) << 3;
    const int r4  = (lane >> 4) << 2;

    const u16*   aptr16 = (const u16*)Av + (size_t)(m0 + row) * lda + kq;
    const float* aptrf  = (const float*)Av + (size_t)(m0 + row) * lda + kq;
    const u16*   bptr   = Bt + (size_t)(n0 + row) * ldb + kq;

    f32x4 acc00 = {0.f,0.f,0.f,0.f}, acc01 = {0.f,0.f,0.f,0.f};
    f32x4 acc10 = {0.f,0.f,0.f,0.f}, acc11 = {0.f,0.f,0.f,0.f};

    auto loadA = [&](int k0) -> uint4 {
        if (AF32) {
            float4 ax = *(const float4*)(aptrf + k0);
            float4 ay = *(const float4*)(aptrf + k0 + 4);
            uint4 r;
            r.x = pack_bf2(ax.x, ax.y); r.y = pack_bf2(ax.z, ax.w);
            r.z = pack_bf2(ay.x, ay.y); r.w = pack_bf2(ay.z, ay.w);
            return r;
        }
        return *(const uint4*)(aptr16 + k0);
    };

    uint4 a_nxt = loadA(0);
    uint4 b_nxt = *(const uint4*)bptr;

    for (int k0 = 0; k0 < K; k0 += 32) {
        __syncthreads();
        *(uint4*)&As[row][kq] = a_nxt;
        *(uint4*)&Bs[row][kq] = b_nxt;
        if (k0 + 32 < K) {
            a_nxt = loadA(k0 + 32);
            b_nxt = *(const uint4*)(bptr + k0 + 32);
        }
        __syncthreads();
        bf16x8 af0 = *(const bf16x8*)&As[wr + l16][lk8];
        bf16x8 af1 = *(const bf16x8*)&As[wr + 16 + l16][lk8];
        bf16x8 bf0 = *(const bf16x8*)&Bs[wc + l16][lk8];
        bf16x8 bf1 = *(const bf16x8*)&Bs[wc + 16 + l16][lk8];
        acc00 = __builtin_amdgcn_mfma_f32_16x16x32_bf16(af0, bf0, acc00, 0, 0, 0);
        acc01 = __builtin_amdgcn_mfma_f32_16x16x32_bf16(af0, bf1, acc01, 0, 0, 0);
        acc10 = __builtin_amdgcn_mfma_f32_16x16x32_bf16(af1, bf0, acc10, 0, 0, 0);
        acc11 = __builtin_amdgcn_mfma_f32_16x16x32_bf16(af1, bf1, acc11, 0, 0, 0);
    }

#define EPI_FRAG(ACC, MF, NF)                                                  \
    {                                                                          \
        const int gcol = n0 + wc + (NF)*16 + l16;                              \
        const float bv = bias ? bias[gcol] : 0.f;                              \
        float v_[4];                                                           \
        _Pragma("unroll")                                                      \
        for (int r = 0; r < 4; r++) {                                          \
            float v = ACC[r] + bv;                                             \
            if (RELU) v = fmaxf(v, 0.f);                                       \
            v_[r] = v;                                                         \
        }                                                                      \
        const int lr0 = wr + (MF)*16 + r4;                                     \
        if (MODE == 3) {                                                       \
            const int lc = wc + (NF)*16 + l16;                                 \
            _Pragma("unroll")                                                  \
            for (int r = 0; r < 4; r++) Ts[lc][lr0 + r] = f16bits((f16)v_[r]); \
        } else {                                                               \
            _Pragma("unroll")                                                  \
            for (int r = 0; r < 4; r++) {                                      \
                const size_t off = (size_t)(m0 + lr0 + r) * ldc + gcol;        \
                if (MODE == 0) ((float*)C)[off] = v_[r];                       \
                else if (MODE == 1) ((u16*)C)[off] = f2bf(v_[r]);              \
                else ((u16*)C)[off] = f16bits((f16)v_[r]);                     \
            }                                                                  \
        }                                                                      \
    }
    EPI_FRAG(acc00, 0, 0) EPI_FRAG(acc01, 0, 1)
    EPI_FRAG(acc10, 1, 0) EPI_FRAG(acc11, 1, 1)
#undef EPI_FRAG

    if (MODE == 3) {
        __syncthreads();
        u16* cb = (u16*)C + (size_t)(m0 >> 7) * (768 * 128) + (m0 & 127);
#pragma unroll
        for (int u = 0; u < 4; u++) {
            const int i = tid + u * 256;
            const int hl = i >> 4;
            const int s4 = (i & 15) << 2;
            ushort4 o;
            o.x = Ts[hl][s4 + 0]; o.y = Ts[hl][s4 + 1];
            o.z = Ts[hl][s4 + 2]; o.w = Ts[hl][s4 + 3];
            *(ushort4*)(cb + (size_t)(n0 + hl) * 128 + s4) = o;
        }
    }
}

// ---------------------------------------------------------------------------
// K0: weight transpose+convert only. grid 8064.
// ---------------------------------------------------------------------------
__global__ __launch_bounds__(256) void prep_kernel(
    const float* __restrict__ W1, const float* __restrict__ Wf1,
    const float* __restrict__ Wf2,
    u16* __restrict__ w1t, u16* __restrict__ wf1t, u16* __restrict__ wf2t)
{
    const int tid = threadIdx.x;
    int bid = blockIdx.x;
    const float* in; u16* outp; int tx, ty;
    if (bid < 4608) {
        const int z = bid / 1152, r = bid % 1152;
        tx = r % 24; ty = r / 24;
        in = W1 + (size_t)z * 1536 * 768; outp = w1t + (size_t)z * 768 * 1536;
    } else if (bid < 6912) {
        const int r = bid - 4608;
        tx = r % 48; ty = r / 48;
        in = Wf1; outp = wf1t;
    } else {
        const int r = bid - 6912;
        tx = r % 24; ty = r / 24;
        in = Wf2; outp = wf2t;
    }
    const int C = (bid >= 4608 && bid < 6912) ? 1536 : 768;
    const int c0 = tx * 32, r0 = ty * 32;
    __shared__ float tile[32][33];
    const int tr = tid >> 3, tc = (tid & 7) << 2;
    float4 v = *(const float4*)(in + (size_t)(r0 + tr) * C + c0 + tc);
    tile[tr][tc] = v.x; tile[tr][tc + 1] = v.y;
    tile[tr][tc + 2] = v.z; tile[tr][tc + 3] = v.w;
    __syncthreads();
    ushort4 o;
    o.x = f2bf(tile[tc + 0][tr]); o.y = f2bf(tile[tc + 1][tr]);
    o.z = f2bf(tile[tc + 2][tr]); o.w = f2bf(tile[tc + 3][tr]);
    *(ushort4*)(outp + (size_t)(c0 + tr) * 1536 + r0 + tc) = o;
}

// K1: 8 GEMMs (f32 A direct) -> sx (b1 folded, f16 rows), py_t (f16 transposed).
__global__ __launch_bounds__(256) void gemm_sxpy_kernel(
    const float* __restrict__ sp, const float* __restrict__ ph,
    const u16* __restrict__ w1t, const float* __restrict__ b1,
    u16* __restrict__ sxf, u16* __restrict__ pyt)
{
    const int z = blockIdx.z;
    const int n = z & 3;
    const bool ispy = z >= 4;
    const u16* Bt = w1t + (size_t)n * 768 * 1536 + (ispy ? 768 : 0);
    if (!ispy) {
        gemm_mfma_body<false, 2, true>(sp, 768, Bt, 1536, b1 + n * HD_,
                                       sxf + (size_t)n * M_ * HD_, HD_, 768,
                                       blockIdx.y * 64, blockIdx.x * 64);
    } else {
        gemm_mfma_body<false, 3, true>(ph, 768, Bt, 1536, nullptr,
                                       pyt + (size_t)n * 4 * 768 * 128, 0, 768,
                                       blockIdx.y * 64, blockIdx.x * 64);
    }
}

template<bool RELU, int MODE>
__global__ __launch_bounds__(256) void gemm_mfma_kernel(
    const u16* __restrict__ A, int lda,
    const u16* __restrict__ Bt, int ldb,
    const float* __restrict__ bias,
    void* __restrict__ C, int ldc, int K)
{
    gemm_mfma_body<RELU, MODE, false>(A, lda, Bt, ldb, bias, C, ldc, K,
                                      blockIdx.y * 64, blockIdx.x * 64);
}

// ---------------------------------------------------------------------------
// K2: fused scores+softmax+head-mean+context+concat.
// grid 256 = (b, t-pair), 512 threads = 8 waves; wave (n,r) = head n, row r.
// Batched uint4 LDS reads (round-2 geometry); py panel shared by 2 waves.
// ---------------------------------------------------------------------------
__global__ __launch_bounds__(512) void scores_ctx_kernel(
    const u16* __restrict__ sxf,     // f16 [n][512][768]
    const u16* __restrict__ pyt,     // f16 [n][b][768][128]
    const float* __restrict__ w2,    // f32 [n][768]
    const float* __restrict__ phon,  // f32 [b][128][768]
    const float* __restrict__ speech,// f32 [b][128][768]
    u16* __restrict__ fused)         // bf16 [512][1536]
{
    const int bid = blockIdx.x;
    const int b = bid >> 6, t0 = (bid & 63) * 2;
    const int m0 = b * 128 + t0;
    const int tid = threadIdx.x, lane = tid & 63;
    const int W = tid >> 6;              // wave 0..7
    const int n = W >> 1, r = W & 1;     // head, row

    __shared__ __align__(16) f16x2 sxs[4][2][768];  // 24576 B
    __shared__ __align__(16) f16x2 w2s[4][768];     // 12288 B
    __shared__ float attn4[4][2][128];              //  4096 B
    __shared__ float attn[2][128];                  //  1024 B

    // wave (n,r) stages its row's sx (splatted); waves r==0 stage w2s[n]
#pragma unroll
    for (int q = 0; q < 3; q++) {
        const int u = lane + 64 * q;     // 0..191 ushort4-units
        const int h4 = u * 4;
        ushort4 v = *(const ushort4*)(sxf + ((size_t)(n * 512 + m0 + r)) * 768 + h4);
        sxs[n][r][h4 + 0] = bcast2(splat2(v.x));
        sxs[n][r][h4 + 1] = bcast2(splat2(v.y));
        sxs[n][r][h4 + 2] = bcast2(splat2(v.z));
        sxs[n][r][h4 + 3] = bcast2(splat2(v.w));
        if (r == 0) {
            float4 wv = *(const float4*)(w2 + n * 768 + h4);
            w2s[n][h4 + 0] = bcast2(splat2(f16bits((f16)wv.x)));
            w2s[n][h4 + 1] = bcast2(splat2(f16bits((f16)wv.y)));
            w2s[n][h4 + 2] = bcast2(splat2(f16bits((f16)wv.z)));
            w2s[n][h4 + 3] = bcast2(splat2(f16bits((f16)wv.w)));
        }
    }
    __syncthreads();

    const f16x2* pypanel = (const f16x2*)(pyt + ((size_t)((n << 2) | b)) * 768 * 128) + lane;
    const f16x2 z2 = {(f16)0, (f16)0};

    float acc0 = 0.f, acc1 = 0.f;        // s = 2*lane, 2*lane+1

    f16x2 b0[16], b1[16];
#pragma unroll
    for (int j = 0; j < 16; j++) b0[j] = pypanel[(size_t)j * 64];
#pragma unroll
    for (int j = 0; j < 16; j++) b1[j] = pypanel[(size_t)(16 + j) * 64];

    auto compute = [&](const f16x2 (&buf)[16], int hbase, f16x2 (&a4)[4]) {
#pragma unroll
        for (int j4 = 0; j4 < 16; j4 += 4) {
            uint4 sau = *(const uint4*)&sxs[n][r][hbase + j4];
            uint4 wvu = *(const uint4*)&w2s[n][hbase + j4];
            const u32 sa_[4] = {sau.x, sau.y, sau.z, sau.w};
            const u32 wv_[4] = {wvu.x, wvu.y, wvu.z, wvu.w};
#pragma unroll
            for (int j = 0; j < 4; j++) {
                f16x2 r_ = __builtin_elementwise_max(bcast2(sa_[j]) + buf[j4 + j], z2);
                a4[j] = __builtin_elementwise_fma(r_, bcast2(wv_[j]), a4[j]);
            }
        }
    };

    for (int hc = 0; hc < 768; hc += 32) {
        f16x2 a4[4] = {z2, z2, z2, z2};
        compute(b0, hc, a4);
        if (hc + 32 < 768) {
#pragma unroll
            for (int j = 0; j < 16; j++) b0[j] = pypanel[(size_t)(hc + 32 + j) * 64];
        }
        compute(b1, hc + 16, a4);
        if (hc + 48 < 768) {
#pragma unroll
            for (int j = 0; j < 16; j++) b1[j] = pypanel[(size_t)(hc + 48 + j) * 64];
        }
#pragma unroll
        for (int k = 0; k < 4; k++) {
            acc0 += (float)a4[k].x;
            acc1 += (float)a4[k].y;
        }
    }

    // in-wave softmax over this row's 128 scores (2/lane), 0.25-scaled
    float mx = fmaxf(acc0, acc1);
#pragma unroll
    for (int off = 32; off; off >>= 1) mx = fmaxf(mx, __shfl_xor(mx, off, 64));
    const float e0 = expf(acc0 - mx), e1 = expf(acc1 - mx);
    float sm = e0 + e1;
#pragma unroll
    for (int off = 32; off; off >>= 1) sm += __shfl_xor(sm, off, 64);
    const float inv = 0.25f / sm;
    float2 pr; pr.x = e0 * inv; pr.y = e1 * inv;
    *(float2*)&attn4[n][r][2 * lane] = pr;
    __syncthreads();

    // deterministic head reduction: 256 slots (2 rows x 128 s)
    if (tid < 256) {
        const int rr = tid >> 7, s = tid & 127;
        attn[rr][s] = attn4[0][rr][s] + attn4[1][rr][s] + attn4[2][rr][s] + attn4[3][rr][s];
    }
    __syncthreads();

    // context matvec + concat: row = tid>>8, 3 d-chunks of 256 per row
    {
        const int rr = tid >> 8;
        const int dbase = tid & 255;
        const int m = m0 + rr;
        const float* ph = phon + (size_t)b * 128 * 768;
#pragma unroll
        for (int j = 0; j < 3; j++) {
            const int d = dbase + 256 * j;
            float acc = 0.f;
#pragma unroll 8
            for (int s = 0; s < 128; s++)
                acc = fmaf(attn[rr][s], ph[(size_t)s * 768 + d], acc);
            fused[(size_t)m * 1536 + d] = f2bf(speech[(size_t)m * 768 + d]);
            fused[(size_t)m * 1536 + 768 + d] = f2bf(acc);
        }
    }
}

// K5: fused LN stats + time-mean. grid 12 = (b, 256-d chunk); stats redundant x3.
__global__ __launch_bounds__(256) void ln_fused_kernel(
    const float* __restrict__ x, const float* __restrict__ g,
    const float* __restrict__ lb, float* __restrict__ out)
{
    const int b = blockIdx.x / 3, c = blockIdx.x % 3;
    const int tid = threadIdx.x, lane = tid & 63, w = tid >> 6;
    __shared__ float rs[T1_];
    __shared__ float Sred[4];

    float prsum = 0.f;
    for (int i = 0; i < 32; i++) {
        const int row = w * 32 + i;
        const float4* x4 = (const float4*)(x + ((size_t)(b * T1_ + row)) * D_);
        float s = 0.f, ss = 0.f;
#pragma unroll
        for (int j = 0; j < 3; j++) {
            float4 v = x4[j * 64 + lane];
            s += v.x + v.y + v.z + v.w;
            ss += v.x * v.x + v.y * v.y + v.z * v.z + v.w * v.w;
        }
#pragma unroll
        for (int off = 32; off; off >>= 1) {
            s += __shfl_xor(s, off, 64);
            ss += __shfl_xor(ss, off, 64);
        }
        if (lane == 0) {
            const float mu = s * (1.f / D_);
            const float var = ss * (1.f / D_) - mu * mu;
            const float r = rsqrtf(var + LN_EPS_);
            rs[row] = r;
            prsum += mu * r;
        }
    }
    if (lane == 0) Sred[w] = prsum;
    __syncthreads();
    const float S = Sred[0] + Sred[1] + Sred[2] + Sred[3];
    const float* xb = x + (size_t)b * T1_ * D_;
    const int d = c * 256 + tid;
    float acc = 0.f;
#pragma unroll 8
    for (int t = 0; t < T1_; t++)
        acc = fmaf(xb[(size_t)t * D_ + d], rs[t], acc);
    out[b * D_ + d] = g[d] * (acc - S) * (1.f / T1_) + lb[d];
}

extern "C" void kernel_launch(void* const* d_in, const int* in_sizes, int n_in,
                              void* d_out, int out_size, void* d_ws, size_t ws_size,
                              hipStream_t stream)
{
    const float* speech = (const float*)d_in[0];
    const float* phon   = (const float*)d_in[1];
    const float* W1     = (const float*)d_in[2];
    const float* b1     = (const float*)d_in[3];
    const float* w2     = (const float*)d_in[4];
    // d_in[5] = b2: softmax-invariant, unused
    const float* Wf1    = (const float*)d_in[6];
    const float* bf1    = (const float*)d_in[7];
    const float* Wf2    = (const float*)d_in[8];
    const float* bf2    = (const float*)d_in[9];
    const float* ln_g   = (const float*)d_in[10];
    const float* ln_b   = (const float*)d_in[11];
    float* out = (float*)d_out;

    char* w = (char*)d_ws;
    auto alloc = [&](size_t bytes) { char* p = w; w += (bytes + 1023) & ~(size_t)1023; return p; };
    u16* w1t    = (u16*)alloc((size_t)NH_ * 768 * 1536 * 2);
    u16* wf1t   = (u16*)alloc((size_t)1536 * 1536 * 2);
    u16* wf2t   = (u16*)alloc((size_t)768 * 1536 * 2);
    u16* sxf    = (u16*)alloc((size_t)NH_ * M_ * HD_ * 2);        // f16
    u16* pyt    = (u16*)alloc((size_t)NH_ * B_ * 768 * 128 * 2);  // f16 transposed
    u16* fusedb = (u16*)alloc((size_t)M_ * 2 * D_ * 2);
    u16* hbuf   = (u16*)alloc((size_t)M_ * 2 * HD_ * 2);
    float* outpre = (float*)alloc((size_t)M_ * D_ * 4);

    hipLaunchKernelGGL(prep_kernel, dim3(8064), dim3(256), 0, stream,
                       W1, Wf1, Wf2, w1t, wf1t, wf2t);
    hipLaunchKernelGGL(gemm_sxpy_kernel, dim3(HD_ / 64, M_ / 64, 8), dim3(256), 0, stream,
                       speech, phon, w1t, b1, sxf, pyt);
    hipLaunchKernelGGL(scores_ctx_kernel, dim3(256), dim3(512), 0, stream,
                       sxf, pyt, w2, phon, speech, fusedb);
    hipLaunchKernelGGL((gemm_mfma_kernel<true, 1>), dim3(2 * HD_ / 64, M_ / 64), dim3(256), 0, stream,
                       fusedb, 2 * D_, wf1t, 1536, bf1, hbuf, 2 * HD_, 2 * D_);
    hipLaunchKernelGGL((gemm_mfma_kernel<false, 0>), dim3(D_ / 64, M_ / 64), dim3(256), 0, stream,
                       hbuf, 2 * HD_, wf2t, 1536, bf2, outpre, D_, 2 * HD_);
    hipLaunchKernelGGL(ln_fused_kernel, dim3(12), dim3(256), 0, stream,
                       outpre, ln_g, ln_b, out);
}

// Round 12
// 114.776 us; speedup vs baseline: 1.1196x; 1.1196x over previous
//
#include <hip/hip_runtime.h>
#include <cstddef>

// ----------------------------------------------------------------------------
// AttentionFusion round 11: 6 launches. scores_ctx v3: 4 waves (wave n = head),
// each wave processes BOTH t-rows (round-2's proven 2-rows/wave amortization:
// 3 uint4 LDS reads per 4h feed 2 rows; py loads feed 2 rows). Context uses
// float2-packed attn, register-batched 8 s at a time, phon loads shared
// across rows. Rest identical to round 10.
// ----------------------------------------------------------------------------

#define D_  768
#define HD_ 768
#define NH_ 4
#define B_  4
#define T1_ 128
#define T2_ 128
#define M_  (B_*T1_)
#define LN_EPS_ 1e-5f

typedef unsigned short u16;
typedef unsigned int u32;
typedef _Float16 f16;
typedef _Float16 f16x2 __attribute__((ext_vector_type(2)));
typedef __bf16 bf16x8 __attribute__((ext_vector_type(8)));
typedef float f32x4 __attribute__((ext_vector_type(4)));

__device__ __forceinline__ u16 f2bf(float f) {
    union { float f; unsigned int u; } v; v.f = f;
    unsigned int u = v.u + (0x7FFFu + ((v.u >> 16) & 1u));
    return (u16)(u >> 16);
}
__device__ __forceinline__ u32 pack_bf2(float lo, float hi) {
    return (u32)f2bf(lo) | ((u32)f2bf(hi) << 16);
}
__device__ __forceinline__ u16 f16bits(f16 h) {
    return __builtin_bit_cast(unsigned short, h);
}
__device__ __forceinline__ f16x2 bcast2(u32 u) {
    return __builtin_bit_cast(f16x2, u);
}
__device__ __forceinline__ u32 splat2(u16 h) { return (u32)h * 0x10001u; }

// ---------------- bf16 MFMA GEMM: C[M,N] = A[M,K] @ Bt[N,K]^T + bias --------
// AF32: A is f32 (converted to bf16 during staging). Else A is bf16.
// MODE: 0 = f32 rows, 1 = bf16 rows, 2 = f16 rows, 3 = f16 transposed (py_t)
template<bool RELU, int MODE, bool AF32>
__device__ __forceinline__ void gemm_mfma_body(
    const void* __restrict__ Av, int lda,
    const u16* __restrict__ Bt, int ldb,
    const float* __restrict__ bias,
    void* __restrict__ C, int ldc, int K, int m0, int n0)
{
    __shared__ __align__(16) u16 As[64][40];
    __shared__ __align__(16) u16 Bs[64][40];
    __shared__ u16 Ts[MODE == 3 ? 64 : 1][MODE == 3 ? 68 : 1];

    const int tid = threadIdx.x;
    const int row = tid >> 2;
    const int kq  = (tid & 3) << 3;
    const int lane = tid & 63;
    const int w  = tid >> 6;
    const int wr = (w >> 1) << 5;
    const int wc = (w & 1) << 5;
    const int l16 = lane & 15;
    const int lk8 = (lane >> 4) << 3;
    const int r4  = (lane >> 4) << 2;

    const u16*   aptr16 = (const u16*)Av + (size_t)(m0 + row) * lda + kq;
    const float* aptrf  = (const float*)Av + (size_t)(m0 + row) * lda + kq;
    const u16*   bptr   = Bt + (size_t)(n0 + row) * ldb + kq;

    f32x4 acc00 = {0.f,0.f,0.f,0.f}, acc01 = {0.f,0.f,0.f,0.f};
    f32x4 acc10 = {0.f,0.f,0.f,0.f}, acc11 = {0.f,0.f,0.f,0.f};

    auto loadA = [&](int k0) -> uint4 {
        if (AF32) {
            float4 ax = *(const float4*)(aptrf + k0);
            float4 ay = *(const float4*)(aptrf + k0 + 4);
            uint4 r;
            r.x = pack_bf2(ax.x, ax.y); r.y = pack_bf2(ax.z, ax.w);
            r.z = pack_bf2(ay.x, ay.y); r.w = pack_bf2(ay.z, ay.w);
            return r;
        }
        return *(const uint4*)(aptr16 + k0);
    };

    uint4 a_nxt = loadA(0);
    uint4 b_nxt = *(const uint4*)bptr;

    for (int k0 = 0; k0 < K; k0 += 32) {
        __syncthreads();
        *(uint4*)&As[row][kq] = a_nxt;
        *(uint4*)&Bs[row][kq] = b_nxt;
        if (k0 + 32 < K) {
            a_nxt = loadA(k0 + 32);
            b_nxt = *(const uint4*)(bptr + k0 + 32);
        }
        __syncthreads();
        bf16x8 af0 = *(const bf16x8*)&As[wr + l16][lk8];
        bf16x8 af1 = *(const bf16x8*)&As[wr + 16 + l16][lk8];
        bf16x8 bf0 = *(const bf16x8*)&Bs[wc + l16][lk8];
        bf16x8 bf1 = *(const bf16x8*)&Bs[wc + 16 + l16][lk8];
        acc00 = __builtin_amdgcn_mfma_f32_16x16x32_bf16(af0, bf0, acc00, 0, 0, 0);
        acc01 = __builtin_amdgcn_mfma_f32_16x16x32_bf16(af0, bf1, acc01, 0, 0, 0);
        acc10 = __builtin_amdgcn_mfma_f32_16x16x32_bf16(af1, bf0, acc10, 0, 0, 0);
        acc11 = __builtin_amdgcn_mfma_f32_16x16x32_bf16(af1, bf1, acc11, 0, 0, 0);
    }

#define EPI_FRAG(ACC, MF, NF)                                                  \
    {                                                                          \
        const int gcol = n0 + wc + (NF)*16 + l16;                              \
        const float bv = bias ? bias[gcol] : 0.f;                              \
        float v_[4];                                                           \
        _Pragma("unroll")                                                      \
        for (int r = 0; r < 4; r++) {                                          \
            float v = ACC[r] + bv;                                             \
            if (RELU) v = fmaxf(v, 0.f);                                       \
            v_[r] = v;                                                         \
        }                                                                      \
        const int lr0 = wr + (MF)*16 + r4;                                     \
        if (MODE == 3) {                                                       \
            const int lc = wc + (NF)*16 + l16;                                 \
            _Pragma("unroll")                                                  \
            for (int r = 0; r < 4; r++) Ts[lc][lr0 + r] = f16bits((f16)v_[r]); \
        } else {                                                               \
            _Pragma("unroll")                                                  \
            for (int r = 0; r < 4; r++) {                                      \
                const size_t off = (size_t)(m0 + lr0 + r) * ldc + gcol;        \
                if (MODE == 0) ((float*)C)[off] = v_[r];                       \
                else if (MODE == 1) ((u16*)C)[off] = f2bf(v_[r]);              \
                else ((u16*)C)[off] = f16bits((f16)v_[r]);                     \
            }                                                                  \
        }                                                                      \
    }
    EPI_FRAG(acc00, 0, 0) EPI_FRAG(acc01, 0, 1)
    EPI_FRAG(acc10, 1, 0) EPI_FRAG(acc11, 1, 1)
#undef EPI_FRAG

    if (MODE == 3) {
        __syncthreads();
        u16* cb = (u16*)C + (size_t)(m0 >> 7) * (768 * 128) + (m0 & 127);
#pragma unroll
        for (int u = 0; u < 4; u++) {
            const int i = tid + u * 256;
            const int hl = i >> 4;
            const int s4 = (i & 15) << 2;
            ushort4 o;
            o.x = Ts[hl][s4 + 0]; o.y = Ts[hl][s4 + 1];
            o.z = Ts[hl][s4 + 2]; o.w = Ts[hl][s4 + 3];
            *(ushort4*)(cb + (size_t)(n0 + hl) * 128 + s4) = o;
        }
    }
}

// ---------------------------------------------------------------------------
// K0: weight transpose+convert only. grid 8064.
// ---------------------------------------------------------------------------
__global__ __launch_bounds__(256) void prep_kernel(
    const float* __restrict__ W1, const float* __restrict__ Wf1,
    const float* __restrict__ Wf2,
    u16* __restrict__ w1t, u16* __restrict__ wf1t, u16* __restrict__ wf2t)
{
    const int tid = threadIdx.x;
    int bid = blockIdx.x;
    const float* in; u16* outp; int tx, ty;
    if (bid < 4608) {
        const int z = bid / 1152, r = bid % 1152;
        tx = r % 24; ty = r / 24;
        in = W1 + (size_t)z * 1536 * 768; outp = w1t + (size_t)z * 768 * 1536;
    } else if (bid < 6912) {
        const int r = bid - 4608;
        tx = r % 48; ty = r / 48;
        in = Wf1; outp = wf1t;
    } else {
        const int r = bid - 6912;
        tx = r % 24; ty = r / 24;
        in = Wf2; outp = wf2t;
    }
    const int C = (bid >= 4608 && bid < 6912) ? 1536 : 768;
    const int c0 = tx * 32, r0 = ty * 32;
    __shared__ float tile[32][33];
    const int tr = tid >> 3, tc = (tid & 7) << 2;
    float4 v = *(const float4*)(in + (size_t)(r0 + tr) * C + c0 + tc);
    tile[tr][tc] = v.x; tile[tr][tc + 1] = v.y;
    tile[tr][tc + 2] = v.z; tile[tr][tc + 3] = v.w;
    __syncthreads();
    ushort4 o;
    o.x = f2bf(tile[tc + 0][tr]); o.y = f2bf(tile[tc + 1][tr]);
    o.z = f2bf(tile[tc + 2][tr]); o.w = f2bf(tile[tc + 3][tr]);
    *(ushort4*)(outp + (size_t)(c0 + tr) * 1536 + r0 + tc) = o;
}

// K1: 8 GEMMs (f32 A direct) -> sx (b1 folded, f16 rows), py_t (f16 transposed).
__global__ __launch_bounds__(256) void gemm_sxpy_kernel(
    const float* __restrict__ sp, const float* __restrict__ ph,
    const u16* __restrict__ w1t, const float* __restrict__ b1,
    u16* __restrict__ sxf, u16* __restrict__ pyt)
{
    const int z = blockIdx.z;
    const int n = z & 3;
    const bool ispy = z >= 4;
    const u16* Bt = w1t + (size_t)n * 768 * 1536 + (ispy ? 768 : 0);
    if (!ispy) {
        gemm_mfma_body<false, 2, true>(sp, 768, Bt, 1536, b1 + n * HD_,
                                       sxf + (size_t)n * M_ * HD_, HD_, 768,
                                       blockIdx.y * 64, blockIdx.x * 64);
    } else {
        gemm_mfma_body<false, 3, true>(ph, 768, Bt, 1536, nullptr,
                                       pyt + (size_t)n * 4 * 768 * 128, 0, 768,
                                       blockIdx.y * 64, blockIdx.x * 64);
    }
}

template<bool RELU, int MODE>
__global__ __launch_bounds__(256) void gemm_mfma_kernel(
    const u16* __restrict__ A, int lda,
    const u16* __restrict__ Bt, int ldb,
    const float* __restrict__ bias,
    void* __restrict__ C, int ldc, int K)
{
    gemm_mfma_body<RELU, MODE, false>(A, lda, Bt, ldb, bias, C, ldc, K,
                                      blockIdx.y * 64, blockIdx.x * 64);
}

// ---------------------------------------------------------------------------
// K2: fused scores+softmax+head-mean+context+concat.
// grid 256 = (b, t-pair), 256 threads = 4 waves; wave n = head n, BOTH rows.
// Round-2 inner loop: 3 uint4 LDS reads per 4h feed 2 rows; py loads feed 2.
// ---------------------------------------------------------------------------
__global__ __launch_bounds__(256) void scores_ctx_kernel(
    const u16* __restrict__ sxf,     // f16 [n][512][768]
    const u16* __restrict__ pyt,     // f16 [n][b][768][128]
    const float* __restrict__ w2,    // f32 [n][768]
    const float* __restrict__ phon,  // f32 [b][128][768]
    const float* __restrict__ speech,// f32 [b][128][768]
    u16* __restrict__ fused)         // bf16 [512][1536]
{
    const int bid = blockIdx.x;
    const int b = bid >> 6, t0 = (bid & 63) * 2;
    const int m0 = b * 128 + t0;
    const int tid = threadIdx.x, lane = tid & 63;
    const int n = tid >> 6;              // wave = head

    __shared__ __align__(16) f16x2 sxs[4][2][768];  // 24576 B
    __shared__ __align__(16) f16x2 w2s[4][768];     // 12288 B
    __shared__ float attn4[4][2][128];              //  4096 B
    __shared__ float2 attn[128];                    //  1024 B [s]->(row0,row1)

    // wave n stages its head's 2 sx rows (splatted) + w2
#pragma unroll
    for (int r = 0; r < 2; r++)
#pragma unroll
        for (int q = 0; q < 3; q++) {
            const int h4 = (lane + 64 * q) * 4;
            ushort4 v = *(const ushort4*)(sxf + ((size_t)(n * 512 + m0 + r)) * 768 + h4);
            sxs[n][r][h4 + 0] = bcast2(splat2(v.x));
            sxs[n][r][h4 + 1] = bcast2(splat2(v.y));
            sxs[n][r][h4 + 2] = bcast2(splat2(v.z));
            sxs[n][r][h4 + 3] = bcast2(splat2(v.w));
        }
#pragma unroll
    for (int q = 0; q < 3; q++) {
        const int h4 = (lane + 64 * q) * 4;
        float4 wv = *(const float4*)(w2 + n * 768 + h4);
        w2s[n][h4 + 0] = bcast2(splat2(f16bits((f16)wv.x)));
        w2s[n][h4 + 1] = bcast2(splat2(f16bits((f16)wv.y)));
        w2s[n][h4 + 2] = bcast2(splat2(f16bits((f16)wv.z)));
        w2s[n][h4 + 3] = bcast2(splat2(f16bits((f16)wv.w)));
    }
    // wave-private LDS regions: no cross-wave barrier needed before use.

    const f16x2* pypanel = (const f16x2*)(pyt + ((size_t)((n << 2) | b)) * 768 * 128) + lane;
    const f16x2 z2 = {(f16)0, (f16)0};

    float accA0 = 0.f, accA1 = 0.f, accB0 = 0.f, accB1 = 0.f;

    f16x2 b0[16], b1[16];
#pragma unroll
    for (int j = 0; j < 16; j++) b0[j] = pypanel[(size_t)j * 64];
#pragma unroll
    for (int j = 0; j < 16; j++) b1[j] = pypanel[(size_t)(16 + j) * 64];

    auto compute = [&](const f16x2 (&buf)[16], int hbase) {
        f16x2 aA = z2, aB = z2;
#pragma unroll
        for (int j4 = 0; j4 < 16; j4 += 4) {
            uint4 sau = *(const uint4*)&sxs[n][0][hbase + j4];
            uint4 sbu = *(const uint4*)&sxs[n][1][hbase + j4];
            uint4 wvu = *(const uint4*)&w2s[n][hbase + j4];
            const u32 sa_[4] = {sau.x, sau.y, sau.z, sau.w};
            const u32 sb_[4] = {sbu.x, sbu.y, sbu.z, sbu.w};
            const u32 wv_[4] = {wvu.x, wvu.y, wvu.z, wvu.w};
#pragma unroll
            for (int j = 0; j < 4; j++) {
                const f16x2 pv = buf[j4 + j];
                const f16x2 wj = bcast2(wv_[j]);
                f16x2 ra = __builtin_elementwise_max(bcast2(sa_[j]) + pv, z2);
                f16x2 rb = __builtin_elementwise_max(bcast2(sb_[j]) + pv, z2);
                aA = __builtin_elementwise_fma(ra, wj, aA);
                aB = __builtin_elementwise_fma(rb, wj, aB);
            }
        }
        accA0 += (float)aA.x; accA1 += (float)aA.y;
        accB0 += (float)aB.x; accB1 += (float)aB.y;
    };

    for (int hc = 0; hc < 768; hc += 32) {
        compute(b0, hc);
        if (hc + 32 < 768) {
#pragma unroll
            for (int j = 0; j < 16; j++) b0[j] = pypanel[(size_t)(hc + 32 + j) * 64];
        }
        compute(b1, hc + 16);
        if (hc + 48 < 768) {
#pragma unroll
            for (int j = 0; j < 16; j++) b1[j] = pypanel[(size_t)(hc + 48 + j) * 64];
        }
    }

    // softmax per row (2 per wave), 0.25-scaled
#pragma unroll
    for (int which = 0; which < 2; which++) {
        const float s0 = which ? accB0 : accA0;
        const float s1 = which ? accB1 : accA1;
        float mx = fmaxf(s0, s1);
#pragma unroll
        for (int off = 32; off; off >>= 1) mx = fmaxf(mx, __shfl_xor(mx, off, 64));
        const float e0 = expf(s0 - mx), e1 = expf(s1 - mx);
        float sm = e0 + e1;
#pragma unroll
        for (int off = 32; off; off >>= 1) sm += __shfl_xor(sm, off, 64);
        const float inv = 0.25f / sm;
        float2 pr; pr.x = e0 * inv; pr.y = e1 * inv;
        *(float2*)&attn4[n][which][2 * lane] = pr;
    }
    __syncthreads();

    // deterministic head reduction into float2-packed attn[s]
    if (tid < 128) {
        const int s = tid;
        float2 a;
        a.x = attn4[0][0][s] + attn4[1][0][s] + attn4[2][0][s] + attn4[3][0][s];
        a.y = attn4[0][1][s] + attn4[1][1][s] + attn4[2][1][s] + attn4[3][1][s];
        attn[s] = a;
    }
    __syncthreads();

    // context matvec (both rows share phon loads) + concat write
    {
        const float* ph = phon + (size_t)b * 128 * 768;
        const int d0 = tid;
        float acc0[3] = {0.f, 0.f, 0.f};
        float acc1[3] = {0.f, 0.f, 0.f};
        for (int s8 = 0; s8 < 128; s8 += 8) {
            float2 at[8];
#pragma unroll
            for (int k = 0; k < 8; k++) at[k] = attn[s8 + k];
#pragma unroll
            for (int j = 0; j < 3; j++) {
                const int d = d0 + 256 * j;
#pragma unroll
                for (int k = 0; k < 8; k++) {
                    const float pv = ph[(size_t)(s8 + k) * 768 + d];
                    acc0[j] = fmaf(at[k].x, pv, acc0[j]);
                    acc1[j] = fmaf(at[k].y, pv, acc1[j]);
                }
            }
        }
#pragma unroll
        for (int j = 0; j < 3; j++) {
            const int d = d0 + 256 * j;
            fused[(size_t)m0 * 1536 + d] = f2bf(speech[(size_t)m0 * 768 + d]);
            fused[(size_t)m0 * 1536 + 768 + d] = f2bf(acc0[j]);
            fused[(size_t)(m0 + 1) * 1536 + d] = f2bf(speech[(size_t)(m0 + 1) * 768 + d]);
            fused[(size_t)(m0 + 1) * 1536 + 768 + d] = f2bf(acc1[j]);
        }
    }
}

// K5: fused LN stats + time-mean. grid 12 = (b, 256-d chunk); stats redundant x3.
__global__ __launch_bounds__(256) void ln_fused_kernel(
    const float* __restrict__ x, const float* __restrict__ g,
    const float* __restrict__ lb, float* __restrict__ out)
{
    const int b = blockIdx.x / 3, c = blockIdx.x % 3;
    const int tid = threadIdx.x, lane = tid & 63, w = tid >> 6;
    __shared__ float rs[T1_];
    __shared__ float Sred[4];

    float prsum = 0.f;
    for (int i = 0; i < 32; i++) {
        const int row = w * 32 + i;
        const float4* x4 = (const float4*)(x + ((size_t)(b * T1_ + row)) * D_);
        float s = 0.f, ss = 0.f;
#pragma unroll
        for (int j = 0; j < 3; j++) {
            float4 v = x4[j * 64 + lane];
            s += v.x + v.y + v.z + v.w;
            ss += v.x * v.x + v.y * v.y + v.z * v.z + v.w * v.w;
        }
#pragma unroll
        for (int off = 32; off; off >>= 1) {
            s += __shfl_xor(s, off, 64);
            ss += __shfl_xor(ss, off, 64);
        }
        if (lane == 0) {
            const float mu = s * (1.f / D_);
            const float var = ss * (1.f / D_) - mu * mu;
            const float r = rsqrtf(var + LN_EPS_);
            rs[row] = r;
            prsum += mu * r;
        }
    }
    if (lane == 0) Sred[w] = prsum;
    __syncthreads();
    const float S = Sred[0] + Sred[1] + Sred[2] + Sred[3];
    const float* xb = x + (size_t)b * T1_ * D_;
    const int d = c * 256 + tid;
    float acc = 0.f;
#pragma unroll 8
    for (int t = 0; t < T1_; t++)
        acc = fmaf(xb[(size_t)t * D_ + d], rs[t], acc);
    out[b * D_ + d] = g[d] * (acc - S) * (1.f / T1_) + lb[d];
}

extern "C" void kernel_launch(void* const* d_in, const int* in_sizes, int n_in,
                              void* d_out, int out_size, void* d_ws, size_t ws_size,
                              hipStream_t stream)
{
    const float* speech = (const float*)d_in[0];
    const float* phon   = (const float*)d_in[1];
    const float* W1     = (const float*)d_in[2];
    const float* b1     = (const float*)d_in[3];
    const float* w2     = (const float*)d_in[4];
    // d_in[5] = b2: softmax-invariant, unused
    const float* Wf1    = (const float*)d_in[6];
    const float* bf1    = (const float*)d_in[7];
    const float* Wf2    = (const float*)d_in[8];
    const float* bf2    = (const float*)d_in[9];
    const float* ln_g   = (const float*)d_in[10];
    const float* ln_b   = (const float*)d_in[11];
    float* out = (float*)d_out;

    char* w = (char*)d_ws;
    auto alloc = [&](size_t bytes) { char* p = w; w += (bytes + 1023) & ~(size_t)1023; return p; };
    u16* w1t    = (u16*)alloc((size_t)NH_ * 768 * 1536 * 2);
    u16* wf1t   = (u16*)alloc((size_t)1536 * 1536 * 2);
    u16* wf2t   = (u16*)alloc((size_t)768 * 1536 * 2);
    u16* sxf    = (u16*)alloc((size_t)NH_ * M_ * HD_ * 2);        // f16
    u16* pyt    = (u16*)alloc((size_t)NH_ * B_ * 768 * 128 * 2);  // f16 transposed
    u16* fusedb = (u16*)alloc((size_t)M_ * 2 * D_ * 2);
    u16* hbuf   = (u16*)alloc((size_t)M_ * 2 * HD_ * 2);
    float* outpre = (float*)alloc((size_t)M_ * D_ * 4);

    hipLaunchKernelGGL(prep_kernel, dim3(8064), dim3(256), 0, stream,
                       W1, Wf1, Wf2, w1t, wf1t, wf2t);
    hipLaunchKernelGGL(gemm_sxpy_kernel, dim3(HD_ / 64, M_ / 64, 8), dim3(256), 0, stream,
                       speech, phon, w1t, b1, sxf, pyt);
    hipLaunchKernelGGL(scores_ctx_kernel, dim3(256), dim3(256), 0, stream,
                       sxf, pyt, w2, phon, speech, fusedb);
    hipLaunchKernelGGL((gemm_mfma_kernel<true, 1>), dim3(2 * HD_ / 64, M_ / 64), dim3(256), 0, stream,
                       fusedb, 2 * D_, wf1t, 1536, bf1, hbuf, 2 * HD_, 2 * D_);
    hipLaunchKernelGGL((gemm_mfma_kernel<false, 0>), dim3(D_ / 64, M_ / 64), dim3(256), 0, stream,
                       hbuf, 2 * HD_, wf2t, 1536, bf2, outpre, D_, 2 * HD_);
    hipLaunchKernelGGL(ln_fused_kernel, dim3(12), dim3(256), 0, stream,
                       outpre, ln_g, ln_b, out);
}